// Round 4
// baseline (23.628 us; speedup 1.0000x reference)
//
#include <hip/hip_runtime.h>

#define DD 128   // feature dim, fixed by the reference

typedef float v2f __attribute__((ext_vector_type(2)));
typedef float v4f __attribute__((ext_vector_type(4)));

// Packed per-pair update: z = x*a + c; zz = z*z; p *= (1 - zz); s += zz.
#define UPD2(P, S, XX, AA, CC)                                   \
    {                                                            \
        v2f z  = __builtin_elementwise_fma((XX), (AA), (CC));    \
        v2f zz = z * z;                                          \
        P = __builtin_elementwise_fma(-zz, P, P);                \
        S += zz;                                                 \
    }

// Tile: 32 n x 32 b per block, 512 threads (8 waves).
// lane = (half<<5) | ncol : ncol = n-column, half selects 2 of the wave's 4 b-rows.
// LDS: a/c [32 n-rows][32 quads] float4, XOR-swizzled -> 32 KB total -> 4 blocks/CU
// -> up to 8 waves/SIMD (2x the latency hiding of the 64 KB version).
__global__ __launch_bounds__(512, 4)
void wavelet_prod_kernel(const float* __restrict__ x,
                         const float* __restrict__ bias,
                         const float* __restrict__ scale,
                         float* __restrict__ out,
                         int B, int N)
{
    __shared__ v4f a_s[32 * 32];
    __shared__ v4f c_s[32 * 32];

    const int tid  = threadIdx.x;
    const int lane = tid & 63;
    const int wave = tid >> 6;
    const int ncol = lane & 31;
    const int half = lane >> 5;

    const int n0 = blockIdx.x * 32;   // 32 n per block (one per lane-column)
    const int bb = blockIdx.y * 32;   // 32 b per block (4 per wave, 2 per thread)

    // ---- one-time staging: 32 x 128 bias/scale tile -> a = 1/scale, c = -bias/scale ----
    {
        const v4f* b4 = (const v4f*)bias;
        const v4f* s4 = (const v4f*)scale;
        #pragma unroll
        for (int k = 0; k < 2; ++k) {
            int flat = tid + k * 512;          // 0..1023 float4 slots
            int r = flat >> 5;                 // n-row within tile (0..31)
            int q = flat & 31;                 // d-quad (0..31)
            v4f sv = s4[(n0 + r) * 32 + q];
            v4f bv = b4[(n0 + r) * 32 + q];
            v4f av, cv;
            av.x = 1.0f / sv.x; av.y = 1.0f / sv.y;
            av.z = 1.0f / sv.z; av.w = 1.0f / sv.w;
            cv = -bv * av;
            int dst = r * 32 + (q ^ (r & 7));  // XOR swizzle (same scheme as R1/R3)
            a_s[dst] = av;
            c_s[dst] = cv;
        }
    }
    __syncthreads();

    const int r0 = bb + wave * 4 + half * 2;            // first of this thread's 2 b-rows
    const v4f* xr = (const v4f*)(x + (size_t)r0 * DD);  // rows stride 32 quads

    const v4f* arow = a_s + ncol * 32;
    const v4f* crow = c_s + ncol * 32;
    const int sw = ncol & 7;

    v2f p0 = {1.f, 1.f}, p1 = {1.f, 1.f};
    v2f s0 = {0.f, 0.f}, s1 = {0.f, 0.f};

    const float kexp = -0.7213475204444817f;  // -0.5 * log2(e)

    #pragma unroll
    for (int f = 0; f < 8; ++f) {             // 8 folds of 16 d
        #pragma unroll
        for (int cc = 0; cc < 4; ++cc) {      // 4 quads of 4 d
            const int q    = f * 4 + cc;
            const int slot = q ^ sw;          // shared by a & c; 2 lanes/addr -> broadcast
            v4f av = arow[slot];
            v4f cv = crow[slot];
            v4f x0 = xr[q];                   // row r0   (uniform per 32-lane half)
            v4f x1 = xr[32 + q];              // row r0+1
            UPD2(p0, s0, x0.lo, av.lo, cv.lo);
            UPD2(p0, s0, x0.hi, av.hi, cv.hi);
            UPD2(p1, s1, x1.lo, av.lo, cv.lo);
            UPD2(p1, s1, x1.hi, av.hi, cv.hi);
        }
        // Fold Gaussian factor + merge packed chains every 16 d (bounded partials).
        p0.x = p0.x * p0.y * __builtin_amdgcn_exp2f((s0.x + s0.y) * kexp);
        p0.y = 1.f; s0 = (v2f){0.f, 0.f};
        p1.x = p1.x * p1.y * __builtin_amdgcn_exp2f((s1.x + s1.y) * kexp);
        p1.y = 1.f; s1 = (v2f){0.f, 0.f};
    }

    out[(size_t)r0 * N + n0 + ncol]       = p0.x;
    out[(size_t)(r0 + 1) * N + n0 + ncol] = p1.x;
}

extern "C" void kernel_launch(void* const* d_in, const int* in_sizes, int n_in,
                              void* d_out, int out_size, void* d_ws, size_t ws_size,
                              hipStream_t stream)
{
    const float* x     = (const float*)d_in[0];
    const float* bias  = (const float*)d_in[1];
    const float* scale = (const float*)d_in[2];
    float* out = (float*)d_out;

    const int B = in_sizes[0] / DD;   // 2048
    const int N = in_sizes[1] / DD;   // 512

    dim3 grid(N / 32, B / 32);        // (16, 64) = 1024 blocks, 4 per CU, zero tail
    wavelet_prod_kernel<<<grid, 512, 0, stream>>>(x, bias, scale, out, B, N);
}